// Round 1
// baseline (377.997 us; speedup 1.0000x reference)
//
#include <hip/hip_runtime.h>
#include <math.h>

#define N 512
#define CS 384
#define CZ 128
#define NH 16
#define DH 24
#define HD 384
#define NN (N*N)
#define EPS 1e-5f

// ws layout (float offsets)
#define OFF_AN   0          // a_n [N][CS]
#define OFF_QT   196608     // qT [H][N][D] (pre-scaled by 1/sqrt(24))
#define OFF_KT   393216     // kT [H][N][D]
#define OFF_VT   589824     // vT [H][N][D]
#define OFF_GT   786432     // gT [H][N][D] (sigmoid applied)
#define OFF_OG   983040     // o*g [N][HD]
#define OFF_WZ2  1179648    // g_z*Wz transposed [H][CZ]
#define OFF_SH   1181696    // [H]
#define OFF_BH   1181712    // [H]
#define OFF_BIAS 1181728    // pair bias [H][N][N]

// ---------------- prep: Wz2[h][c] = g_z[c]*Wz[c][h]; Sh, Bh ----------------
__global__ void prep_kernel(const float* __restrict__ g_z, const float* __restrict__ lnb_z,
                            const float* __restrict__ Wz, const float* __restrict__ bz,
                            float* __restrict__ ws) {
    int t = threadIdx.x;
    float* Wz2 = ws + OFF_WZ2;
    for (int i = t; i < NH * CZ; i += 256) {
        int h = i >> 7, c = i & (CZ - 1);
        Wz2[h * CZ + c] = g_z[c] * Wz[c * NH + h];
    }
    if (t < NH) {
        float s = 0.f, b = 0.f;
        for (int c = 0; c < CZ; ++c) {
            float w = Wz[c * NH + t];
            s += g_z[c] * w;
            b += lnb_z[c] * w;
        }
        ws[OFF_SH + t] = s;
        ws[OFF_BH + t] = b + bz[t];
    }
}

// ---------------- LayerNorm of a: one block per row ----------------
__global__ void ln_a_kernel(const float* __restrict__ a, const float* __restrict__ g_a,
                            const float* __restrict__ b_a, float* __restrict__ ws) {
    int r = blockIdx.x, t = threadIdx.x; // block 128
    const float* row = a + r * CS;
    float x0 = row[t], x1 = row[t + 128], x2 = row[t + 256];
    float s1 = x0 + x1 + x2;
    float s2 = x0 * x0 + x1 * x1 + x2 * x2;
    #pragma unroll
    for (int m = 1; m < 64; m <<= 1) {
        s1 += __shfl_xor(s1, m, 64);
        s2 += __shfl_xor(s2, m, 64);
    }
    __shared__ float ls1[2], ls2[2];
    if ((t & 63) == 0) { ls1[t >> 6] = s1; ls2[t >> 6] = s2; }
    __syncthreads();
    s1 = ls1[0] + ls1[1];
    s2 = ls2[0] + ls2[1];
    float mu = s1 * (1.f / CS);
    float var = s2 * (1.f / CS) - mu * mu;
    float rs = rsqrtf(var + EPS);
    float* an = ws + OFF_AN + r * CS;
    an[t]       = (x0 - mu) * rs * g_a[t]       + b_a[t];
    an[t + 128] = (x1 - mu) * rs * g_a[t + 128] + b_a[t + 128];
    an[t + 256] = (x2 - mu) * rs * g_a[t + 256] + b_a[t + 256];
}

// ---------------- q,k,v,g projections (scalar-B GEMM, 16 cols/thread) ----------------
// grid (24, 8), block 256. wave -> 16-col strip of [Wq|Wk|Wv|Wg]; lane -> row.
__global__ void __launch_bounds__(256) qkvg_kernel(const float* __restrict__ Wq, const float* __restrict__ Wk,
                                                   const float* __restrict__ Wv, const float* __restrict__ Wg,
                                                   const float* __restrict__ bg, float* __restrict__ ws) {
    const int lane = threadIdx.x & 63;
    const int w = __builtin_amdgcn_readfirstlane(threadIdx.x >> 6);
    const int strip = blockIdx.x * 4 + w;     // 0..95
    const int n0 = strip * 16;
    const int sel = n0 / HD;                  // 0:q 1:k 2:v 3:g
    const int col = n0 % HD;
    const float* Wm = (sel == 0) ? Wq : (sel == 1) ? Wk : (sel == 2) ? Wv : Wg;
    const int m = blockIdx.y * 64 + lane;
    const float* arow = ws + OFF_AN + m * CS;
    float acc[16];
    #pragma unroll
    for (int j = 0; j < 16; ++j) acc[j] = 0.f;
    for (int kb = 0; kb < CS; kb += 32) {
        float4 av[8];
        #pragma unroll
        for (int i = 0; i < 8; ++i) av[i] = ((const float4*)(arow + kb))[i]; // full 128B line
        #pragma unroll
        for (int i = 0; i < 8; ++i) {
            const float* wr = Wm + (kb + i * 4) * HD + col; // wave-uniform -> s_load
            #pragma unroll
            for (int j = 0; j < 16; ++j) {
                acc[j] += av[i].x * wr[j];
                acc[j] += av[i].y * wr[HD + j];
                acc[j] += av[i].z * wr[2 * HD + j];
                acc[j] += av[i].w * wr[3 * HD + j];
            }
        }
    }
    float* dst = ws + ((sel == 0) ? OFF_QT : (sel == 1) ? OFF_KT : (sel == 2) ? OFF_VT : OFF_GT);
    if (sel == 3) {
        #pragma unroll
        for (int j = 0; j < 16; ++j) acc[j] = 1.f / (1.f + __expf(-(acc[j] + bg[col + j])));
    } else if (sel == 0) {
        #pragma unroll
        for (int j = 0; j < 16; ++j) acc[j] *= 0.20412414523193153f; // 1/sqrt(24)
    }
    #pragma unroll
    for (int j = 0; j < 16; ++j) {
        int c = col + j;
        int h = c / DH, d = c % DH;
        dst[(h * N + m) * DH + d] = acc[j];
    }
}

// ---------------- fused z-LN + z_n@Wz -> pair bias [H][N][N] ----------------
// one (i,j) row of z per lane; 8 back-to-back float4 loads = 1 cacheline/lane (MSHR merge)
__global__ void __launch_bounds__(256) pairbias_kernel(const float* __restrict__ z, float* __restrict__ ws) {
    const int row = blockIdx.x * 256 + threadIdx.x; // 0..262143
    const float* zr = z + (size_t)row * CZ;
    const float* Wz2 = ws + OFF_WZ2;
    float dots[NH];
    #pragma unroll
    for (int h = 0; h < NH; ++h) dots[h] = 0.f;
    float s1 = 0.f, s2 = 0.f;
    #pragma unroll
    for (int cb = 0; cb < CZ; cb += 32) {
        float4 zv[8];
        #pragma unroll
        for (int i = 0; i < 8; ++i) zv[i] = ((const float4*)(zr + cb))[i];
        #pragma unroll
        for (int i = 0; i < 8; ++i) {
            s1 += zv[i].x + zv[i].y + zv[i].z + zv[i].w;
            s2 += zv[i].x * zv[i].x + zv[i].y * zv[i].y + zv[i].z * zv[i].z + zv[i].w * zv[i].w;
            const float* wc = Wz2 + cb + i * 4; // uniform -> s_load
            #pragma unroll
            for (int h = 0; h < NH; ++h) {
                dots[h] += zv[i].x * wc[h * CZ]     + zv[i].y * wc[h * CZ + 1]
                         + zv[i].z * wc[h * CZ + 2] + zv[i].w * wc[h * CZ + 3];
            }
        }
    }
    float mu = s1 * (1.f / CZ);
    float var = s2 * (1.f / CZ) - mu * mu;
    float r = rsqrtf(var + EPS);
    float* bias = ws + OFF_BIAS;
    #pragma unroll
    for (int h = 0; h < NH; ++h)
        bias[h * NN + row] = r * (dots[h] - mu * ws[OFF_SH + h]) + ws[OFF_BH + h];
}

// ---------------- attention: block=(h, 16 q); wave = 4 q, 16 lanes/q over k ----------------
__global__ void __launch_bounds__(256, 2) attn_kernel(float* __restrict__ ws) {
    const int lane = threadIdx.x & 63;
    const int w = __builtin_amdgcn_readfirstlane(threadIdx.x >> 6);
    const int qi = lane >> 4;        // 0..3 within wave
    const int klane = lane & 15;     // 0..15
    const int h = blockIdx.y;
    const int q = blockIdx.x * 16 + w * 4 + qi;
    const float* qT = ws + OFF_QT + h * N * DH;
    const float* kT = ws + OFF_KT + h * N * DH;
    const float* vT = ws + OFF_VT + h * N * DH;
    const float* gT = ws + OFF_GT + h * N * DH;
    const float* bias = ws + OFF_BIAS + h * NN;

    float qv[DH];
    #pragma unroll
    for (int d6 = 0; d6 < 6; ++d6) {
        float4 t4 = ((const float4*)(qT + q * DH))[d6];
        qv[d6 * 4 + 0] = t4.x; qv[d6 * 4 + 1] = t4.y; qv[d6 * 4 + 2] = t4.z; qv[d6 * 4 + 3] = t4.w;
    }
    float sc[32];
    #pragma unroll
    for (int t = 0; t < 32; ++t) {
        const int kk = t * 16 + klane;
        float kv[DH];
        #pragma unroll
        for (int d6 = 0; d6 < 6; ++d6) {
            float4 t4 = ((const float4*)(kT + kk * DH))[d6];
            kv[d6 * 4 + 0] = t4.x; kv[d6 * 4 + 1] = t4.y; kv[d6 * 4 + 2] = t4.z; kv[d6 * 4 + 3] = t4.w;
        }
        float s = 0.f;
        #pragma unroll
        for (int d = 0; d < DH; ++d) s += qv[d] * kv[d];
        sc[t] = s + bias[q * N + kk];
    }
    // softmax over 512 = 32 local x 16 lanes
    float mx = sc[0];
    #pragma unroll
    for (int t = 1; t < 32; ++t) mx = fmaxf(mx, sc[t]);
    #pragma unroll
    for (int m = 1; m < 16; m <<= 1) mx = fmaxf(mx, __shfl_xor(mx, m, 64));
    float sum = 0.f;
    #pragma unroll
    for (int t = 0; t < 32; ++t) { sc[t] = __expf(sc[t] - mx); sum += sc[t]; }
    #pragma unroll
    for (int m = 1; m < 16; m <<= 1) sum += __shfl_xor(sum, m, 64);
    float inv = 1.f / sum;
    #pragma unroll
    for (int t = 0; t < 32; ++t) sc[t] *= inv;
    // P @ V
    float acc[DH];
    #pragma unroll
    for (int d = 0; d < DH; ++d) acc[d] = 0.f;
    #pragma unroll
    for (int t = 0; t < 32; ++t) {
        const int kk = t * 16 + klane;
        float vv[DH];
        #pragma unroll
        for (int d6 = 0; d6 < 6; ++d6) {
            float4 t4 = ((const float4*)(vT + kk * DH))[d6];
            vv[d6 * 4 + 0] = t4.x; vv[d6 * 4 + 1] = t4.y; vv[d6 * 4 + 2] = t4.z; vv[d6 * 4 + 3] = t4.w;
        }
        #pragma unroll
        for (int d = 0; d < DH; ++d) acc[d] += sc[t] * vv[d];
    }
    #pragma unroll
    for (int m = 1; m < 16; m <<= 1) {
        #pragma unroll
        for (int d = 0; d < DH; ++d) acc[d] += __shfl_xor(acc[d], m, 64);
    }
    // extract (avoid dynamic VGPR indexing) + gate + store o*g
    float o1 = 0.f, o2 = 0.f;
    #pragma unroll
    for (int d = 0; d < 16; ++d) o1 = (klane == d) ? acc[d] : o1;
    #pragma unroll
    for (int d = 16; d < 24; ++d) o2 = (klane == (d - 16)) ? acc[d] : o2;
    float* og = ws + OFF_OG;
    og[q * HD + h * DH + klane] = o1 * gT[q * DH + klane];
    if (klane < 8)
        og[q * HD + h * DH + 16 + klane] = o2 * gT[q * DH + 16 + klane];
}

// ---------------- out = og @ Wo + bo ----------------
// grid (12, 8), block 256. wave -> 8-col strip; lane -> row.
__global__ void __launch_bounds__(256) out_gemm_kernel(const float* __restrict__ Wo, const float* __restrict__ bo,
                                                       const float* __restrict__ ws, float* __restrict__ out) {
    const int lane = threadIdx.x & 63;
    const int w = __builtin_amdgcn_readfirstlane(threadIdx.x >> 6);
    const int strip = blockIdx.x * 4 + w;  // 0..47
    const int c0 = strip * 8;
    const int m = blockIdx.y * 64 + lane;
    const float* orow = ws + OFF_OG + m * HD;
    float acc[8];
    #pragma unroll
    for (int j = 0; j < 8; ++j) acc[j] = 0.f;
    for (int kb = 0; kb < HD; kb += 32) {
        float4 av[8];
        #pragma unroll
        for (int i = 0; i < 8; ++i) av[i] = ((const float4*)(orow + kb))[i];
        #pragma unroll
        for (int i = 0; i < 8; ++i) {
            const float* wr = Wo + (kb + i * 4) * CS + c0; // uniform -> s_load
            #pragma unroll
            for (int j = 0; j < 8; ++j) {
                acc[j] += av[i].x * wr[j];
                acc[j] += av[i].y * wr[CS + j];
                acc[j] += av[i].z * wr[2 * CS + j];
                acc[j] += av[i].w * wr[3 * CS + j];
            }
        }
    }
    #pragma unroll
    for (int j = 0; j < 8; ++j) out[m * CS + c0 + j] = acc[j] + bo[c0 + j];
}

extern "C" void kernel_launch(void* const* d_in, const int* in_sizes, int n_in,
                              void* d_out, int out_size, void* d_ws, size_t ws_size,
                              hipStream_t stream) {
    const float* a    = (const float*)d_in[0];
    const float* z    = (const float*)d_in[1];
    const float* g_a  = (const float*)d_in[2];
    const float* b_a  = (const float*)d_in[3];
    const float* g_z  = (const float*)d_in[4];
    const float* b_z  = (const float*)d_in[5];
    const float* Wz   = (const float*)d_in[6];
    const float* bz   = (const float*)d_in[7];
    const float* Wq   = (const float*)d_in[8];
    const float* Wk   = (const float*)d_in[9];
    const float* Wv   = (const float*)d_in[10];
    const float* Wg   = (const float*)d_in[11];
    const float* bg   = (const float*)d_in[12];
    const float* Wo   = (const float*)d_in[13];
    const float* bo   = (const float*)d_in[14];
    float* ws  = (float*)d_ws;
    float* out = (float*)d_out;

    hipLaunchKernelGGL(prep_kernel,     dim3(1),      dim3(256), 0, stream, g_z, b_z, Wz, bz, ws);
    hipLaunchKernelGGL(ln_a_kernel,     dim3(512),    dim3(128), 0, stream, a, g_a, b_a, ws);
    hipLaunchKernelGGL(qkvg_kernel,     dim3(24, 8),  dim3(256), 0, stream, Wq, Wk, Wv, Wg, bg, ws);
    hipLaunchKernelGGL(pairbias_kernel, dim3(1024),   dim3(256), 0, stream, z, ws);
    hipLaunchKernelGGL(attn_kernel,     dim3(32, 16), dim3(256), 0, stream, ws);
    hipLaunchKernelGGL(out_gemm_kernel, dim3(12, 8),  dim3(256), 0, stream, Wo, bo, ws, out);
}

// Round 2
// 338.676 us; speedup vs baseline: 1.1161x; 1.1161x over previous
//
#include <hip/hip_runtime.h>
#include <math.h>

#define N 512
#define CS 384
#define CZ 128
#define NH 16
#define DH 24
#define HD 384
#define NN (N*N)
#define EPS 1e-5f

// ws layout (float offsets)
#define OFF_AN   0          // a_n [N][CS]
#define OFF_QT   196608     // qT [H][N][D] (pre-scaled by 1/sqrt(24))
#define OFF_KT   393216     // kT [H][N][D]
#define OFF_VT   589824     // vT [H][N][D]
#define OFF_GT   786432     // gT [H][N][D] (sigmoid applied)
#define OFF_OG   983040     // o*g [N][HD]
#define OFF_WZ2  1179648    // g_z*Wz transposed [H][CZ]
#define OFF_SH   1181696    // [H]
#define OFF_BH   1181712    // [H]
#define OFF_BIAS 1181728    // pair bias [H][N][N]

// ---------------- prep: Wz2[h][c] = g_z[c]*Wz[c][h]; Sh, Bh (parallel) ----------------
__global__ void prep_kernel(const float* __restrict__ g_z, const float* __restrict__ lnb_z,
                            const float* __restrict__ Wz, const float* __restrict__ bz,
                            float* __restrict__ wz2, float* __restrict__ sh, float* __restrict__ bh) {
    int t = threadIdx.x;
    for (int i = t; i < NH * CZ; i += 256) {
        int h = i >> 7, c = i & (CZ - 1);
        wz2[h * CZ + c] = g_z[c] * Wz[c * NH + h];
    }
    __shared__ float ls[NH][17], lb[NH][17];
    int h = t >> 4, seg = t & 15;
    float s = 0.f, b = 0.f;
    #pragma unroll
    for (int i = 0; i < 8; ++i) {
        int c = seg * 8 + i;
        float w = Wz[c * NH + h];
        s += g_z[c] * w;
        b += lnb_z[c] * w;
    }
    ls[h][seg] = s; lb[h][seg] = b;
    __syncthreads();
    if (t < NH) {
        float ss = 0.f, bb = 0.f;
        #pragma unroll
        for (int i = 0; i < 16; ++i) { ss += ls[t][i]; bb += lb[t][i]; }
        sh[t] = ss;
        bh[t] = bb + bz[t];
    }
}

// ---------------- LayerNorm of a: one block per row ----------------
__global__ void ln_a_kernel(const float* __restrict__ a, const float* __restrict__ g_a,
                            const float* __restrict__ b_a, float* __restrict__ an_out) {
    int r = blockIdx.x, t = threadIdx.x; // block 128
    const float* row = a + r * CS;
    float x0 = row[t], x1 = row[t + 128], x2 = row[t + 256];
    float s1 = x0 + x1 + x2;
    float s2 = x0 * x0 + x1 * x1 + x2 * x2;
    #pragma unroll
    for (int m = 1; m < 64; m <<= 1) {
        s1 += __shfl_xor(s1, m, 64);
        s2 += __shfl_xor(s2, m, 64);
    }
    __shared__ float ls1[2], ls2[2];
    if ((t & 63) == 0) { ls1[t >> 6] = s1; ls2[t >> 6] = s2; }
    __syncthreads();
    s1 = ls1[0] + ls1[1];
    s2 = ls2[0] + ls2[1];
    float mu = s1 * (1.f / CS);
    float var = s2 * (1.f / CS) - mu * mu;
    float rs = rsqrtf(var + EPS);
    float* an = an_out + r * CS;
    an[t]       = (x0 - mu) * rs * g_a[t]       + b_a[t];
    an[t + 128] = (x1 - mu) * rs * g_a[t + 128] + b_a[t + 128];
    an[t + 256] = (x2 - mu) * rs * g_a[t + 256] + b_a[t + 256];
}

// ---------------- q,k,v,g projections (scalar-B GEMM, 8 cols/thread) ----------------
// grid (48, 8), block 256. wave -> 8-col strip of [Wq|Wk|Wv|Wg]; lane -> row. 1536 waves.
__global__ void __launch_bounds__(256) qkvg_kernel(const float* __restrict__ Wq, const float* __restrict__ Wk,
                                                   const float* __restrict__ Wv, const float* __restrict__ Wg,
                                                   const float* __restrict__ bg, const float* __restrict__ an,
                                                   float* __restrict__ qt, float* __restrict__ kt,
                                                   float* __restrict__ vt, float* __restrict__ gt) {
    const int lane = threadIdx.x & 63;
    const int w = __builtin_amdgcn_readfirstlane(threadIdx.x >> 6);
    const int strip = blockIdx.x * 4 + w;     // 0..191
    const int n0 = strip * 8;
    const int sel = n0 / HD;                  // 0:q 1:k 2:v 3:g
    const int col = n0 % HD;
    const float* Wm = (sel == 0) ? Wq : (sel == 1) ? Wk : (sel == 2) ? Wv : Wg;
    const int m = blockIdx.y * 64 + lane;
    const float* arow = an + m * CS;
    float acc[8];
    #pragma unroll
    for (int j = 0; j < 8; ++j) acc[j] = 0.f;
    for (int kb = 0; kb < CS; kb += 32) {
        float4 av[8];
        #pragma unroll
        for (int i = 0; i < 8; ++i) av[i] = ((const float4*)(arow + kb))[i]; // full 128B line
        #pragma unroll
        for (int i = 0; i < 8; ++i) {
            const float* wr = Wm + (kb + i * 4) * HD + col; // wave-uniform -> s_load
            #pragma unroll
            for (int j = 0; j < 8; ++j) {
                acc[j] += av[i].x * wr[j];
                acc[j] += av[i].y * wr[HD + j];
                acc[j] += av[i].z * wr[2 * HD + j];
                acc[j] += av[i].w * wr[3 * HD + j];
            }
        }
    }
    float* dst = (sel == 0) ? qt : (sel == 1) ? kt : (sel == 2) ? vt : gt;
    if (sel == 3) {
        #pragma unroll
        for (int j = 0; j < 8; ++j) acc[j] = 1.f / (1.f + __expf(-(acc[j] + bg[col + j])));
    } else if (sel == 0) {
        #pragma unroll
        for (int j = 0; j < 8; ++j) acc[j] *= 0.20412414523193153f; // 1/sqrt(24)
    }
    #pragma unroll
    for (int j = 0; j < 8; ++j) {
        int c = col + j;
        int h = c / DH, d = c % DH;
        dst[(h * N + m) * DH + d] = acc[j];
    }
}

// ---------------- fused z-LN + z_n@Wz -> pair bias [H][N][N] ----------------
// one (i,j) row of z per lane; weights via SMEM (separate restrict pointer!); h-outer loop
__global__ void __launch_bounds__(256) pairbias_kernel(const float* __restrict__ z,
                                                       const float* __restrict__ wz2,
                                                       const float* __restrict__ sh,
                                                       const float* __restrict__ bh,
                                                       float* __restrict__ bias) {
    const int row = blockIdx.x * 256 + threadIdx.x; // 0..262143
    const float* zr = z + (size_t)row * CZ;
    float dots[NH];
    #pragma unroll
    for (int h = 0; h < NH; ++h) dots[h] = 0.f;
    float s1 = 0.f, s2 = 0.f;
    #pragma unroll
    for (int cb = 0; cb < CZ; cb += 32) {
        float4 zv[8];
        #pragma unroll
        for (int i = 0; i < 8; ++i) zv[i] = ((const float4*)(zr + cb))[i]; // 128B line/lane
        #pragma unroll
        for (int i = 0; i < 8; ++i) {
            s1 += zv[i].x + zv[i].y + zv[i].z + zv[i].w;
            s2 += zv[i].x * zv[i].x + zv[i].y * zv[i].y + zv[i].z * zv[i].z + zv[i].w * zv[i].w;
        }
        #pragma unroll
        for (int h = 0; h < NH; ++h) {
            const float* wrow = wz2 + h * CZ + cb; // wave-uniform, read-only -> s_load
            float d = dots[h];
            #pragma unroll
            for (int i = 0; i < 8; ++i) {
                d += zv[i].x * wrow[i * 4 + 0];
                d += zv[i].y * wrow[i * 4 + 1];
                d += zv[i].z * wrow[i * 4 + 2];
                d += zv[i].w * wrow[i * 4 + 3];
            }
            dots[h] = d;
        }
    }
    float mu = s1 * (1.f / CZ);
    float var = s2 * (1.f / CZ) - mu * mu;
    float r = rsqrtf(var + EPS);
    #pragma unroll
    for (int h = 0; h < NH; ++h)
        bias[h * NN + row] = r * (dots[h] - mu * sh[h]) + bh[h];
}

// ---------------- attention: 2 q per wave, 32 lanes per q over k. 4096 waves ----------------
__global__ void __launch_bounds__(256) attn_kernel(const float* __restrict__ qt, const float* __restrict__ kt,
                                                   const float* __restrict__ vt, const float* __restrict__ gt,
                                                   const float* __restrict__ bias, float* __restrict__ og) {
    const int lane = threadIdx.x & 63;
    const int w = __builtin_amdgcn_readfirstlane(threadIdx.x >> 6);
    const int qhalf = lane >> 5;     // 0/1
    const int klane = lane & 31;
    const int h = blockIdx.y;
    const int q = blockIdx.x * 8 + w * 2 + qhalf;
    const float* qT = qt + h * N * DH;
    const float* kT = kt + h * N * DH;
    const float* vT = vt + h * N * DH;

    float qv[DH];
    #pragma unroll
    for (int d6 = 0; d6 < 6; ++d6) {
        float4 t4 = ((const float4*)(qT + q * DH))[d6];
        qv[d6 * 4 + 0] = t4.x; qv[d6 * 4 + 1] = t4.y; qv[d6 * 4 + 2] = t4.z; qv[d6 * 4 + 3] = t4.w;
    }
    float sc[16];
    #pragma unroll
    for (int t = 0; t < 16; ++t) {
        const int kk = t * 32 + klane;
        const float4* kr = (const float4*)(kT + kk * DH);
        float4 k0 = kr[0], k1 = kr[1], k2 = kr[2], k3 = kr[3], k4 = kr[4], k5 = kr[5];
        float s = qv[0]*k0.x + qv[1]*k0.y + qv[2]*k0.z + qv[3]*k0.w
                + qv[4]*k1.x + qv[5]*k1.y + qv[6]*k1.z + qv[7]*k1.w
                + qv[8]*k2.x + qv[9]*k2.y + qv[10]*k2.z + qv[11]*k2.w
                + qv[12]*k3.x + qv[13]*k3.y + qv[14]*k3.z + qv[15]*k3.w
                + qv[16]*k4.x + qv[17]*k4.y + qv[18]*k4.z + qv[19]*k4.w
                + qv[20]*k5.x + qv[21]*k5.y + qv[22]*k5.z + qv[23]*k5.w;
        sc[t] = s + bias[h * NN + q * N + kk];
    }
    float mx = sc[0];
    #pragma unroll
    for (int t = 1; t < 16; ++t) mx = fmaxf(mx, sc[t]);
    #pragma unroll
    for (int m = 1; m < 32; m <<= 1) mx = fmaxf(mx, __shfl_xor(mx, m, 64));
    float sum = 0.f;
    #pragma unroll
    for (int t = 0; t < 16; ++t) { sc[t] = __expf(sc[t] - mx); sum += sc[t]; }
    #pragma unroll
    for (int m = 1; m < 32; m <<= 1) sum += __shfl_xor(sum, m, 64);
    float inv = 1.f / sum;
    #pragma unroll
    for (int t = 0; t < 16; ++t) sc[t] *= inv;
    float acc[DH];
    #pragma unroll
    for (int d = 0; d < DH; ++d) acc[d] = 0.f;
    #pragma unroll
    for (int t = 0; t < 16; ++t) {
        const int kk = t * 32 + klane;
        const float4* vr = (const float4*)(vT + kk * DH);
        float4 v0 = vr[0], v1 = vr[1], v2 = vr[2], v3 = vr[3], v4 = vr[4], v5 = vr[5];
        float p = sc[t];
        acc[0] += p*v0.x;  acc[1] += p*v0.y;  acc[2] += p*v0.z;  acc[3] += p*v0.w;
        acc[4] += p*v1.x;  acc[5] += p*v1.y;  acc[6] += p*v1.z;  acc[7] += p*v1.w;
        acc[8] += p*v2.x;  acc[9] += p*v2.y;  acc[10] += p*v2.z; acc[11] += p*v2.w;
        acc[12] += p*v3.x; acc[13] += p*v3.y; acc[14] += p*v3.z; acc[15] += p*v3.w;
        acc[16] += p*v4.x; acc[17] += p*v4.y; acc[18] += p*v4.z; acc[19] += p*v4.w;
        acc[20] += p*v5.x; acc[21] += p*v5.y; acc[22] += p*v5.z; acc[23] += p*v5.w;
    }
    #pragma unroll
    for (int m = 1; m < 32; m <<= 1) {
        #pragma unroll
        for (int d = 0; d < DH; ++d) acc[d] += __shfl_xor(acc[d], m, 64);
    }
    float o = 0.f;
    #pragma unroll
    for (int d = 0; d < DH; ++d) o = (klane == d) ? acc[d] : o;
    if (klane < DH) {
        float g = gt[h * N * DH + q * DH + klane];
        og[q * HD + h * DH + klane] = o * g;
    }
}

// ---------------- out = og @ Wo + bo (4 cols/thread, 768 waves) ----------------
__global__ void __launch_bounds__(256) out_gemm_kernel(const float* __restrict__ Wo, const float* __restrict__ bo,
                                                       const float* __restrict__ og, float* __restrict__ out) {
    const int lane = threadIdx.x & 63;
    const int w = __builtin_amdgcn_readfirstlane(threadIdx.x >> 6);
    const int strip = blockIdx.x * 4 + w;  // 0..95
    const int c0 = strip * 4;
    const int m = blockIdx.y * 64 + lane;
    const float* orow = og + m * HD;
    float acc[4];
    #pragma unroll
    for (int j = 0; j < 4; ++j) acc[j] = 0.f;
    for (int kb = 0; kb < HD; kb += 32) {
        float4 av[8];
        #pragma unroll
        for (int i = 0; i < 8; ++i) av[i] = ((const float4*)(orow + kb))[i];
        #pragma unroll
        for (int i = 0; i < 8; ++i) {
            const float* wr = Wo + (kb + i * 4) * CS + c0; // uniform -> s_load
            #pragma unroll
            for (int j = 0; j < 4; ++j) {
                acc[j] += av[i].x * wr[j];
                acc[j] += av[i].y * wr[CS + j];
                acc[j] += av[i].z * wr[2 * CS + j];
                acc[j] += av[i].w * wr[3 * CS + j];
            }
        }
    }
    #pragma unroll
    for (int j = 0; j < 4; ++j) out[m * CS + c0 + j] = acc[j] + bo[c0 + j];
}

extern "C" void kernel_launch(void* const* d_in, const int* in_sizes, int n_in,
                              void* d_out, int out_size, void* d_ws, size_t ws_size,
                              hipStream_t stream) {
    const float* a    = (const float*)d_in[0];
    const float* z    = (const float*)d_in[1];
    const float* g_a  = (const float*)d_in[2];
    const float* b_a  = (const float*)d_in[3];
    const float* g_z  = (const float*)d_in[4];
    const float* b_z  = (const float*)d_in[5];
    const float* Wz   = (const float*)d_in[6];
    const float* bz   = (const float*)d_in[7];
    const float* Wq   = (const float*)d_in[8];
    const float* Wk   = (const float*)d_in[9];
    const float* Wv   = (const float*)d_in[10];
    const float* Wg   = (const float*)d_in[11];
    const float* bg   = (const float*)d_in[12];
    const float* Wo   = (const float*)d_in[13];
    const float* bo   = (const float*)d_in[14];
    float* ws  = (float*)d_ws;
    float* out = (float*)d_out;

    float* an   = ws + OFF_AN;
    float* qt   = ws + OFF_QT;
    float* kt   = ws + OFF_KT;
    float* vt   = ws + OFF_VT;
    float* gt   = ws + OFF_GT;
    float* ogp  = ws + OFF_OG;
    float* wz2  = ws + OFF_WZ2;
    float* shp  = ws + OFF_SH;
    float* bhp  = ws + OFF_BH;
    float* bias = ws + OFF_BIAS;

    hipLaunchKernelGGL(prep_kernel,     dim3(1),      dim3(256), 0, stream, g_z, b_z, Wz, bz, wz2, shp, bhp);
    hipLaunchKernelGGL(ln_a_kernel,     dim3(512),    dim3(128), 0, stream, a, g_a, b_a, an);
    hipLaunchKernelGGL(qkvg_kernel,     dim3(48, 8),  dim3(256), 0, stream, Wq, Wk, Wv, Wg, bg, an, qt, kt, vt, gt);
    hipLaunchKernelGGL(pairbias_kernel, dim3(1024),   dim3(256), 0, stream, z, wz2, shp, bhp, bias);
    hipLaunchKernelGGL(attn_kernel,     dim3(64, 16), dim3(256), 0, stream, qt, kt, vt, gt, bias, ogp);
    hipLaunchKernelGGL(out_gemm_kernel, dim3(24, 8),  dim3(256), 0, stream, Wo, bo, ogp, out);
}